// Round 5
// baseline (154.346 us; speedup 1.0000x reference)
//
#include <hip/hip_runtime.h>

// Chamfer loss: pred (8,4096,3) f32, target (8,4096,3) f32 -> scalar f32.
// dist = |q|^2 + (|t|^2 - 2 q.t). Inner loop: 3-FMA chain seeded from
// precomputed |t|^2; |q|^2 added after the loop. 2 targets/iter ->
// fminf(fminf(d0,d1),mn) fuses to v_min3_f32 => 3.5 VALU/pair.
//
// Round-5 structure: ONE fused kernel (R2-best main loop, NCH=32) + a 256 B
// ctrl memset. Cross-chunk reduction fused via last-block-done counters
// (rocPRIM pattern): per-group atomic counter -> group-last block reduces its
// 32 slots, atomicAdds to a ws accumulator; globally-last writes out[0].
// Round-3/4 post-mortem: per-graph-node overhead (~4-6 us each) dominated, so
// node count goes 3-4 -> 2.

#define BATCH 8
#define NPTS  4096
#define TPB   256
#define Q     8                     // queries per thread
#define QTILE (TPB * Q)             // 2048 queries per block
#define NQT   (NPTS / QTILE)        // 2
#define NQ_TOTAL (2 * BATCH * NPTS) // 65536 query slots (both directions)

#define NCHF   32                   // chunks per group (R2-best)
#define CHUNKF (NPTS / NCHF)        // 128 targets staged per block
#define NGROUPS (2 * BATCH * NQT)   // 32 groups of NCHF blocks

// ctrl layout (u32 words): [0..31] group counters, [32] global counter,
// [33] float accumulator. memset to 0 each call.
#define CTRL_WORDS 64

__global__ __launch_bounds__(TPB, 4)
void chamfer_fused(const float* __restrict__ pred,
                   const float* __restrict__ tgt,
                   float* __restrict__ part /* [NCHF][NQ_TOTAL] */,
                   unsigned int* __restrict__ ctrl,
                   float* __restrict__ out)
{
    int bid = blockIdx.x;
    int g   = bid / NCHF;            // group = dir*16 + b*2 + qt
    int ch  = bid - g * NCHF;
    int dir = g >> 4;
    int b   = (g >> 1) & 7;
    int qt  = g & 1;

    const float* qsrc = dir ? tgt  : pred;
    const float* csrc = dir ? pred : tgt;

    // ---- stage CHUNKF targets into LDS as float4(x,y,z,|t|^2) ----
    __shared__ float4 sc[CHUNKF];
    {
        const float* cbase = csrc + (size_t)(b * NPTS + ch * CHUNKF) * 3;
        for (int p = threadIdx.x; p < CHUNKF; p += TPB) {
            float x = cbase[3 * p + 0];
            float y = cbase[3 * p + 1];
            float z = cbase[3 * p + 2];
            sc[p] = make_float4(x, y, z, x * x + y * y + z * z);
        }
    }

    // ---- per-thread query setup (overlaps staging; barrier after) ----
    float ax[Q], ay[Q], az[Q], w[Q], mn[Q];
    const int q0 = qt * QTILE + threadIdx.x;
#pragma unroll
    for (int i = 0; i < Q; ++i) {
        int q = q0 + i * TPB;
        const float* qp = qsrc + (size_t)(b * NPTS + q) * 3;
        float x = qp[0], y = qp[1], z = qp[2];
        ax[i] = -2.0f * x;
        ay[i] = -2.0f * y;
        az[i] = -2.0f * z;
        w[i]  = x * x + y * y + z * z;
        mn[i] = 3.0e38f;
    }
    __syncthreads();

    // ---- main loop: 3.5 VALU/pair ----
#pragma unroll 4
    for (int j = 0; j < CHUNKF; j += 2) {
        float4 t0 = sc[j];           // uniform addr -> ds_read_b128 broadcast
        float4 t1 = sc[j + 1];
#pragma unroll
        for (int i = 0; i < Q; ++i) {
            float d0 = fmaf(az[i], t0.z, fmaf(ay[i], t0.y, fmaf(ax[i], t0.x, t0.w)));
            float d1 = fmaf(az[i], t1.z, fmaf(ay[i], t1.y, fmaf(ax[i], t1.x, t1.w)));
            mn[i] = fminf(fminf(d0, d1), mn[i]);   // v_min3_f32
        }
    }

    // ---- store this chunk's per-query mins (coalesced) ----
    float* pbase = part + (size_t)dir * (BATCH * NPTS) + (size_t)b * NPTS;
#pragma unroll
    for (int i = 0; i < Q; ++i)
        pbase[(size_t)ch * NQ_TOTAL + q0 + i * TPB] = w[i] + mn[i];

    // ---- release + group counter ----
    __threadfence();                 // agent-scope: L2 writeback across XCDs
    __shared__ unsigned int lastv;
    if (threadIdx.x == 0) lastv = atomicAdd(&ctrl[g], 1u);
    __syncthreads();
    if (lastv != NCHF - 1) return;

    // ---- group-last block: min across NCHF chunks, sum, accumulate ----
    __threadfence();                 // acquire: invalidate caches before reads
    float m[Q];
#pragma unroll
    for (int i = 0; i < Q; ++i)
        m[i] = pbase[q0 + i * TPB];  // chunk 0
    for (int c = 1; c < NCHF; ++c) {
        const float* row = pbase + (size_t)c * NQ_TOTAL;
#pragma unroll
        for (int i = 0; i < Q; ++i)
            m[i] = fminf(m[i], row[q0 + i * TPB]);
    }
    float s = 0.0f;
#pragma unroll
    for (int i = 0; i < Q; ++i) s += m[i];

#pragma unroll
    for (int o = 32; o; o >>= 1) s += __shfl_down(s, o);
    __shared__ float acc[TPB / 64];
    int lane = threadIdx.x & 63, wid = threadIdx.x >> 6;
    if (lane == 0) acc[wid] = s;
    __syncthreads();
    if (threadIdx.x == 0) {
        float bs = 0.0f;
#pragma unroll
        for (int i = 0; i < TPB / 64; ++i) bs += acc[i];
        atomicAdd((float*)&ctrl[33], bs);
        __threadfence();
        unsigned int gdone = atomicAdd(&ctrl[32], 1u);
        if (gdone == NGROUPS - 1) {
            float tot = atomicAdd((float*)&ctrl[33], 0.0f);  // coherent read
            out[0] = tot * (1.0f / (BATCH * NPTS));
        }
    }
}

// ---- secondary path (>=256 KB ws): atomicMin on uint-encoded nonneg floats ----
#define CHUNK 512
#define NCH   (NPTS / CHUNK)

__global__ __launch_bounds__(TPB)
void chamfer_partial_min(const float* __restrict__ pred,
                         const float* __restrict__ tgt,
                         unsigned int* __restrict__ mins)
{
    int bid = blockIdx.x;
    const int per_dir = BATCH * NQT * NCH;
    int dir = bid / per_dir;
    int r   = bid - dir * per_dir;
    int b   = r / (NQT * NCH);
    r      -= b * (NQT * NCH);
    int qt  = r / NCH;
    int ch  = r - qt * NCH;

    const float* qsrc = dir ? tgt  : pred;
    const float* csrc = dir ? pred : tgt;
    unsigned int* mout = mins + (size_t)dir * (BATCH * NPTS) + (size_t)b * NPTS;

    __shared__ float4 sc[CHUNK];
    {
        const float* cbase = csrc + (size_t)(b * NPTS + ch * CHUNK) * 3;
        for (int p = threadIdx.x; p < CHUNK; p += TPB) {
            float x = cbase[3 * p + 0];
            float y = cbase[3 * p + 1];
            float z = cbase[3 * p + 2];
            sc[p] = make_float4(x, y, z, x * x + y * y + z * z);
        }
    }
    __syncthreads();

    float ax[Q], ay[Q], az[Q], w[Q], mn[Q];
    const int q0 = qt * QTILE + threadIdx.x;
#pragma unroll
    for (int i = 0; i < Q; ++i) {
        int q = q0 + i * TPB;
        const float* qp = qsrc + (size_t)(b * NPTS + q) * 3;
        float x = qp[0], y = qp[1], z = qp[2];
        ax[i] = -2.0f * x; ay[i] = -2.0f * y; az[i] = -2.0f * z;
        w[i]  = x * x + y * y + z * z;
        mn[i] = 3.0e38f;
    }
#pragma unroll 4
    for (int j = 0; j < CHUNK; j += 2) {
        float4 t0 = sc[j], t1 = sc[j + 1];
#pragma unroll
        for (int i = 0; i < Q; ++i) {
            float d0 = fmaf(az[i], t0.z, fmaf(ay[i], t0.y, fmaf(ax[i], t0.x, t0.w)));
            float d1 = fmaf(az[i], t1.z, fmaf(ay[i], t1.y, fmaf(ax[i], t1.x, t1.w)));
            mn[i] = fminf(fminf(d0, d1), mn[i]);
        }
    }
#pragma unroll
    for (int i = 0; i < Q; ++i)
        atomicMin(&mout[q0 + i * TPB], __float_as_uint(fmaxf(w[i] + mn[i], 0.0f)));
}

__global__ __launch_bounds__(1024)
void chamfer_reduce(const unsigned int* __restrict__ mins,
                    float* __restrict__ out)
{
    float s0 = 0.0f, s1 = 0.0f;
    for (int i = threadIdx.x; i < BATCH * NPTS; i += 1024) {
        s0 += __uint_as_float(mins[i]);
        s1 += __uint_as_float(mins[BATCH * NPTS + i]);
    }
#pragma unroll
    for (int o = 32; o; o >>= 1) { s0 += __shfl_down(s0, o); s1 += __shfl_down(s1, o); }
    __shared__ float a0[16], a1[16];
    int lane = threadIdx.x & 63, wid = threadIdx.x >> 6;
    if (lane == 0) { a0[wid] = s0; a1[wid] = s1; }
    __syncthreads();
    if (threadIdx.x == 0) {
        float t0 = 0.0f, t1 = 0.0f;
#pragma unroll
        for (int i = 0; i < 16; ++i) { t0 += a0[i]; t1 += a1[i]; }
        out[0] = (t0 + t1) * (1.0f / (BATCH * NPTS));
    }
}

// ---- tertiary path (no usable ws) ----
__global__ __launch_bounds__(TPB)
void chamfer_fallback(const float* __restrict__ pred,
                      const float* __restrict__ tgt,
                      float* __restrict__ out)
{
    int bid = blockIdx.x;
    const int per_dir = BATCH * (NPTS / TPB);
    int dir = bid / per_dir;
    int r   = bid - dir * per_dir;
    int b   = r / (NPTS / TPB);
    int qt  = r % (NPTS / TPB);

    const float* qsrc = dir ? tgt  : pred;
    const float* csrc = dir ? pred : tgt;

    __shared__ float4 sc[CHUNK];
    int q = qt * TPB + threadIdx.x;
    const float* qp = qsrc + (size_t)(b * NPTS + q) * 3;
    float x = qp[0], y = qp[1], z = qp[2];
    float ax = -2.0f * x, ay = -2.0f * y, az = -2.0f * z;
    float w = x * x + y * y + z * z;
    float mn = 3.0e38f;

    for (int ch = 0; ch < NCH; ++ch) {
        __syncthreads();
        const float* cbase = csrc + (size_t)(b * NPTS + ch * CHUNK) * 3;
        for (int p = threadIdx.x; p < CHUNK; p += TPB) {
            float tx = cbase[3 * p + 0];
            float ty = cbase[3 * p + 1];
            float tz = cbase[3 * p + 2];
            sc[p] = make_float4(tx, ty, tz, tx * tx + ty * ty + tz * tz);
        }
        __syncthreads();
#pragma unroll 4
        for (int j = 0; j < CHUNK; ++j) {
            float4 t = sc[j];
            float d = fmaf(az, t.z, fmaf(ay, t.y, fmaf(ax, t.x, t.w)));
            mn = fminf(mn, d);
        }
    }
    mn += w;
#pragma unroll
    for (int o = 32; o; o >>= 1) mn += __shfl_down(mn, o);
    __shared__ float acc[TPB / 64];
    int lane = threadIdx.x & 63, wid = threadIdx.x >> 6;
    if (lane == 0) acc[wid] = mn;
    __syncthreads();
    if (threadIdx.x == 0) {
        float s = 0.0f;
#pragma unroll
        for (int i = 0; i < TPB / 64; ++i) s += acc[i];
        atomicAdd(out, s * (1.0f / (BATCH * NPTS)));
    }
}

extern "C" void kernel_launch(void* const* d_in, const int* in_sizes, int n_in,
                              void* d_out, int out_size, void* d_ws, size_t ws_size,
                              hipStream_t stream)
{
    const float* pred = (const float*)d_in[0];
    const float* tgt  = (const float*)d_in[1];
    float* out = (float*)d_out;

    const size_t part_bytes = (size_t)NCHF * NQ_TOTAL * sizeof(float);   // 8 MB
    const size_t ctrl_bytes = CTRL_WORDS * sizeof(unsigned int);         // 256 B
    const size_t need_fused = part_bytes + ctrl_bytes;
    const size_t need_amin  = (size_t)NQ_TOTAL * sizeof(unsigned int);   // 256 KB

    if (ws_size >= need_fused) {
        float* part = (float*)d_ws;
        unsigned int* ctrl = (unsigned int*)((char*)d_ws + part_bytes);
        hipMemsetAsync(ctrl, 0, ctrl_bytes, stream);
        chamfer_fused<<<NGROUPS * NCHF, TPB, 0, stream>>>(pred, tgt, part, ctrl, out);
    } else if (ws_size >= need_amin) {
        unsigned int* mins = (unsigned int*)d_ws;
        hipMemsetAsync(d_ws, 0x7F, need_amin, stream);
        chamfer_partial_min<<<2 * BATCH * NQT * NCH, TPB, 0, stream>>>(pred, tgt, mins);
        chamfer_reduce<<<1, 1024, 0, stream>>>(mins, out);
    } else {
        hipMemsetAsync(d_out, 0, sizeof(float), stream);
        chamfer_fallback<<<2 * BATCH * (NPTS / TPB), TPB, 0, stream>>>(pred, tgt, out);
    }
}

// Round 6
// 32.200 us; speedup vs baseline: 4.7933x; 4.7933x over previous
//
#include <hip/hip_runtime.h>

// Chamfer loss: pred (8,4096,3) f32, target (8,4096,3) f32 -> scalar f32.
// dist = |q|^2 + (|t|^2 - 2 q.t). Inner loop: 3-FMA chain seeded from
// precomputed |t|^2 (in LDS); |q|^2 added after the loop. 2 targets/iter ->
// fminf(fminf(d0,d1),mn) fuses to v_min3_f32 => 3.5 VALU/pair.
//
// Round-6 structure: TWO graph nodes (R5 lesson: in-kernel cross-XCD fences
// cause per-block L2 writeback-invalidate storms — 7 GB refetch; the
// between-dispatch flush is the cheap way to get cross-XCD visibility).
//   node 1: chamfer_min_slots (1024 blocks, 4/CU) — also zeroes out[0]
//   node 2: chamfer_reduce_slots (64 blocks) — atomicAdd into out[0]
// Setup tax cut vs R2: thread owns 8 CONSECUTIVE queries -> 6 coalesced
// dwordx4 query loads (was 24 strided scalars) and 2 dwordx4 part stores.

#define BATCH 8
#define NPTS  4096
#define TPB   256
#define Q     8                     // queries per thread (consecutive)
#define QTILE (TPB * Q)             // 2048 queries per block
#define NQT   (NPTS / QTILE)        // 2
#define NQ_TOTAL (2 * BATCH * NPTS) // 65536 query slots (both directions)

#define NCHF   32                   // chunks (R2-best)
#define CHUNKF (NPTS / NCHF)        // 128 targets staged per block

__global__ __launch_bounds__(TPB, 4)
void chamfer_min_slots(const float* __restrict__ pred,
                       const float* __restrict__ tgt,
                       float* __restrict__ part /* [NCHF][NQ_TOTAL] */,
                       float* __restrict__ out)
{
    int bid = blockIdx.x;
    int g   = bid >> 5;              // g = dir*16 + b*2 + qt
    int ch  = bid & (NCHF - 1);
    int dir = g >> 4;
    int b   = (g >> 1) & 7;
    int qt  = g & 1;

    if (bid == 0 && threadIdx.x == 0) out[0] = 0.0f;  // read by node 2 only

    const float* qsrc = dir ? tgt  : pred;
    const float* csrc = dir ? pred : tgt;

    // ---- stage CHUNKF targets into LDS as float4(x,y,z,|t|^2) ----
    __shared__ float4 sc[CHUNKF];
    {
        const float* cbase = csrc + (size_t)(b * NPTS + ch * CHUNKF) * 3;
        for (int p = threadIdx.x; p < CHUNKF; p += TPB) {
            float x = cbase[3 * p + 0];
            float y = cbase[3 * p + 1];
            float z = cbase[3 * p + 2];
            sc[p] = make_float4(x, y, z, x * x + y * y + z * z);
        }
    }

    // ---- query setup: 6 coalesced dwordx4 loads = 8 consecutive queries ----
    const float* qbase = qsrc + ((size_t)b * NPTS + (size_t)qt * QTILE) * 3;
    const float4* q4 = reinterpret_cast<const float4*>(qbase);
    float4 v0 = q4[threadIdx.x * 6 + 0];
    float4 v1 = q4[threadIdx.x * 6 + 1];
    float4 v2 = q4[threadIdx.x * 6 + 2];
    float4 v3 = q4[threadIdx.x * 6 + 3];
    float4 v4 = q4[threadIdx.x * 6 + 4];
    float4 v5 = q4[threadIdx.x * 6 + 5];

    float ax[Q], ay[Q], az[Q], w[Q], mn[Q];
    {
        float qx[Q], qy[Q], qz[Q];
        qx[0]=v0.x; qy[0]=v0.y; qz[0]=v0.z;
        qx[1]=v0.w; qy[1]=v1.x; qz[1]=v1.y;
        qx[2]=v1.z; qy[2]=v1.w; qz[2]=v2.x;
        qx[3]=v2.y; qy[3]=v2.z; qz[3]=v2.w;
        qx[4]=v3.x; qy[4]=v3.y; qz[4]=v3.z;
        qx[5]=v3.w; qy[5]=v4.x; qz[5]=v4.y;
        qx[6]=v4.z; qy[6]=v4.w; qz[6]=v5.x;
        qx[7]=v5.y; qy[7]=v5.z; qz[7]=v5.w;
#pragma unroll
        for (int i = 0; i < Q; ++i) {
            ax[i] = -2.0f * qx[i];
            ay[i] = -2.0f * qy[i];
            az[i] = -2.0f * qz[i];
            w[i]  = qx[i]*qx[i] + qy[i]*qy[i] + qz[i]*qz[i];
            mn[i] = 3.0e38f;
        }
    }
    __syncthreads();

    // ---- main loop: 3.5 VALU/pair ----
#pragma unroll 4
    for (int j = 0; j < CHUNKF; j += 2) {
        float4 t0 = sc[j];           // uniform addr -> ds_read_b128 broadcast
        float4 t1 = sc[j + 1];
#pragma unroll
        for (int i = 0; i < Q; ++i) {
            float d0 = fmaf(az[i], t0.z, fmaf(ay[i], t0.y, fmaf(ax[i], t0.x, t0.w)));
            float d1 = fmaf(az[i], t1.z, fmaf(ay[i], t1.y, fmaf(ax[i], t1.x, t1.w)));
            mn[i] = fminf(fminf(d0, d1), mn[i]);   // v_min3_f32
        }
    }

    // ---- store 8 consecutive per-query mins as 2 dwordx4 ----
    float4* prow = reinterpret_cast<float4*>(
        part + (size_t)ch * NQ_TOTAL
             + (size_t)dir * (BATCH * NPTS) + (size_t)b * NPTS
             + (size_t)qt * QTILE);
    prow[threadIdx.x * 2 + 0] = make_float4(w[0]+mn[0], w[1]+mn[1], w[2]+mn[2], w[3]+mn[3]);
    prow[threadIdx.x * 2 + 1] = make_float4(w[4]+mn[4], w[5]+mn[5], w[6]+mn[6], w[7]+mn[7]);
}

// per-query min across NCHF chunks (4 queries/thread via dwordx4),
// block-sum, one atomicAdd per block into out (zeroed by node 1).
__global__ __launch_bounds__(TPB)
void chamfer_reduce_slots(const float* __restrict__ part,
                          float* __restrict__ out)
{
    int idx = blockIdx.x * TPB + threadIdx.x;      // 0..16383
    const float4* p4 = reinterpret_cast<const float4*>(part);
    float4 m = p4[idx];
#pragma unroll 8
    for (int c = 1; c < NCHF; ++c) {
        float4 v = p4[(size_t)c * (NQ_TOTAL / 4) + idx];
        m.x = fminf(m.x, v.x);
        m.y = fminf(m.y, v.y);
        m.z = fminf(m.z, v.z);
        m.w = fminf(m.w, v.w);
    }
    float s = (m.x + m.y) + (m.z + m.w);

#pragma unroll
    for (int o = 32; o; o >>= 1) s += __shfl_down(s, o);
    __shared__ float acc[TPB / 64];
    int lane = threadIdx.x & 63, wid = threadIdx.x >> 6;
    if (lane == 0) acc[wid] = s;
    __syncthreads();
    if (threadIdx.x == 0) {
        float bs = 0.0f;
#pragma unroll
        for (int i = 0; i < TPB / 64; ++i) bs += acc[i];
        atomicAdd(out, bs * (1.0f / (BATCH * NPTS)));
    }
}

// ---- secondary path (>=256 KB ws): atomicMin on uint-encoded nonneg floats ----
#define CHUNK 512
#define NCH   (NPTS / CHUNK)

__global__ __launch_bounds__(TPB)
void chamfer_partial_min(const float* __restrict__ pred,
                         const float* __restrict__ tgt,
                         unsigned int* __restrict__ mins)
{
    int bid = blockIdx.x;
    const int per_dir = BATCH * NQT * NCH;
    int dir = bid / per_dir;
    int r   = bid - dir * per_dir;
    int b   = r / (NQT * NCH);
    r      -= b * (NQT * NCH);
    int qt  = r / NCH;
    int ch  = r - qt * NCH;

    const float* qsrc = dir ? tgt  : pred;
    const float* csrc = dir ? pred : tgt;
    unsigned int* mout = mins + (size_t)dir * (BATCH * NPTS) + (size_t)b * NPTS;

    __shared__ float4 sc[CHUNK];
    {
        const float* cbase = csrc + (size_t)(b * NPTS + ch * CHUNK) * 3;
        for (int p = threadIdx.x; p < CHUNK; p += TPB) {
            float x = cbase[3 * p + 0];
            float y = cbase[3 * p + 1];
            float z = cbase[3 * p + 2];
            sc[p] = make_float4(x, y, z, x * x + y * y + z * z);
        }
    }
    __syncthreads();

    float ax[Q], ay[Q], az[Q], w[Q], mn[Q];
    const int q0 = qt * QTILE + threadIdx.x;
#pragma unroll
    for (int i = 0; i < Q; ++i) {
        int q = q0 + i * TPB;
        const float* qp = qsrc + (size_t)(b * NPTS + q) * 3;
        float x = qp[0], y = qp[1], z = qp[2];
        ax[i] = -2.0f * x; ay[i] = -2.0f * y; az[i] = -2.0f * z;
        w[i]  = x * x + y * y + z * z;
        mn[i] = 3.0e38f;
    }
#pragma unroll 4
    for (int j = 0; j < CHUNK; j += 2) {
        float4 t0 = sc[j], t1 = sc[j + 1];
#pragma unroll
        for (int i = 0; i < Q; ++i) {
            float d0 = fmaf(az[i], t0.z, fmaf(ay[i], t0.y, fmaf(ax[i], t0.x, t0.w)));
            float d1 = fmaf(az[i], t1.z, fmaf(ay[i], t1.y, fmaf(ax[i], t1.x, t1.w)));
            mn[i] = fminf(fminf(d0, d1), mn[i]);
        }
    }
#pragma unroll
    for (int i = 0; i < Q; ++i)
        atomicMin(&mout[q0 + i * TPB], __float_as_uint(fmaxf(w[i] + mn[i], 0.0f)));
}

__global__ __launch_bounds__(1024)
void chamfer_reduce(const unsigned int* __restrict__ mins,
                    float* __restrict__ out)
{
    float s0 = 0.0f, s1 = 0.0f;
    for (int i = threadIdx.x; i < BATCH * NPTS; i += 1024) {
        s0 += __uint_as_float(mins[i]);
        s1 += __uint_as_float(mins[BATCH * NPTS + i]);
    }
#pragma unroll
    for (int o = 32; o; o >>= 1) { s0 += __shfl_down(s0, o); s1 += __shfl_down(s1, o); }
    __shared__ float a0[16], a1[16];
    int lane = threadIdx.x & 63, wid = threadIdx.x >> 6;
    if (lane == 0) { a0[wid] = s0; a1[wid] = s1; }
    __syncthreads();
    if (threadIdx.x == 0) {
        float t0 = 0.0f, t1 = 0.0f;
#pragma unroll
        for (int i = 0; i < 16; ++i) { t0 += a0[i]; t1 += a1[i]; }
        out[0] = (t0 + t1) * (1.0f / (BATCH * NPTS));
    }
}

// ---- tertiary path (no usable ws) ----
__global__ __launch_bounds__(TPB)
void chamfer_fallback(const float* __restrict__ pred,
                      const float* __restrict__ tgt,
                      float* __restrict__ out)
{
    int bid = blockIdx.x;
    const int per_dir = BATCH * (NPTS / TPB);
    int dir = bid / per_dir;
    int r   = bid - dir * per_dir;
    int b   = r / (NPTS / TPB);
    int qt  = r % (NPTS / TPB);

    const float* qsrc = dir ? tgt  : pred;
    const float* csrc = dir ? pred : tgt;

    __shared__ float4 sc[CHUNK];
    int q = qt * TPB + threadIdx.x;
    const float* qp = qsrc + (size_t)(b * NPTS + q) * 3;
    float x = qp[0], y = qp[1], z = qp[2];
    float ax = -2.0f * x, ay = -2.0f * y, az = -2.0f * z;
    float w = x * x + y * y + z * z;
    float mn = 3.0e38f;

    for (int ch = 0; ch < NCH; ++ch) {
        __syncthreads();
        const float* cbase = csrc + (size_t)(b * NPTS + ch * CHUNK) * 3;
        for (int p = threadIdx.x; p < CHUNK; p += TPB) {
            float tx = cbase[3 * p + 0];
            float ty = cbase[3 * p + 1];
            float tz = cbase[3 * p + 2];
            sc[p] = make_float4(tx, ty, tz, tx * tx + ty * ty + tz * tz);
        }
        __syncthreads();
#pragma unroll 4
        for (int j = 0; j < CHUNK; ++j) {
            float4 t = sc[j];
            float d = fmaf(az, t.z, fmaf(ay, t.y, fmaf(ax, t.x, t.w)));
            mn = fminf(mn, d);
        }
    }
    mn += w;
#pragma unroll
    for (int o = 32; o; o >>= 1) mn += __shfl_down(mn, o);
    __shared__ float acc[TPB / 64];
    int lane = threadIdx.x & 63, wid = threadIdx.x >> 6;
    if (lane == 0) acc[wid] = mn;
    __syncthreads();
    if (threadIdx.x == 0) {
        float s = 0.0f;
#pragma unroll
        for (int i = 0; i < TPB / 64; ++i) s += acc[i];
        atomicAdd(out, s * (1.0f / (BATCH * NPTS)));
    }
}

extern "C" void kernel_launch(void* const* d_in, const int* in_sizes, int n_in,
                              void* d_out, int out_size, void* d_ws, size_t ws_size,
                              hipStream_t stream)
{
    const float* pred = (const float*)d_in[0];
    const float* tgt  = (const float*)d_in[1];
    float* out = (float*)d_out;

    const size_t need_slots = (size_t)NCHF * NQ_TOTAL * sizeof(float);   // 8 MB
    const size_t need_amin  = (size_t)NQ_TOTAL * sizeof(unsigned int);   // 256 KB

    if (ws_size >= need_slots) {
        float* part = (float*)d_ws;
        chamfer_min_slots<<<2 * BATCH * NQT * NCHF, TPB, 0, stream>>>(pred, tgt, part, out);
        chamfer_reduce_slots<<<NQ_TOTAL / 4 / TPB, TPB, 0, stream>>>(part, out);
    } else if (ws_size >= need_amin) {
        unsigned int* mins = (unsigned int*)d_ws;
        hipMemsetAsync(d_ws, 0x7F, need_amin, stream);
        chamfer_partial_min<<<2 * BATCH * NQT * NCH, TPB, 0, stream>>>(pred, tgt, mins);
        chamfer_reduce<<<1, 1024, 0, stream>>>(mins, out);
    } else {
        hipMemsetAsync(d_out, 0, sizeof(float), stream);
        chamfer_fallback<<<2 * BATCH * (NPTS / TPB), TPB, 0, stream>>>(pred, tgt, out);
    }
}

// Round 7
// 28.802 us; speedup vs baseline: 5.3589x; 1.1180x over previous
//
#include <hip/hip_runtime.h>

// Chamfer loss: pred (8,4096,3) f32, target (8,4096,3) f32 -> scalar f32.
// dist = |q|^2 + (|t|^2 - 2 q.t). Inner loop: 3-FMA chain seeded from
// precomputed |t|^2 (LDS); |q|^2 added after the cross-slice min.
// 2 targets/iter -> fminf(fminf(d0,d1),mn) fuses to v_min3_f32 (3.5 VALU/pair).
//
// Round-7: full min per query inside ONE block (no cross-block min, no 8 MB
// part round-trip). 512 blocks x 512 threads = 16 qgroups x 32 slices;
// targets staged in 2 LDS phases of 32 KB; in-block LDS reduce across slices;
// block partial -> ws; node 2 = 1-block sum of 512 partials -> out[0]
// (atomic-free, no memset node). 2 graph nodes total.

#define BATCH 8
#define NPTS  4096
#define TPB   512
#define QPT   8                       // queries per thread
#define NQG   16                      // query groups per block
#define QB    (NQG * QPT)             // 128 queries per block
#define NSL   32                      // target slices per block
#define NBLK  (2 * BATCH * (NPTS / QB))  // 512 blocks
#define PHPTS 2048                    // targets staged per phase (32 KB)
#define SLICE (PHPTS / NSL)           // 64 targets per slice per phase

#define INNER_LOOP(SBASE)                                                     \
    _Pragma("unroll 4")                                                       \
    for (int i = 0; i < SLICE; i += 2) {                                      \
        float4 t0 = (SBASE)[i];                                               \
        float4 t1 = (SBASE)[i + 1];                                           \
        _Pragma("unroll")                                                     \
        for (int k = 0; k < QPT; ++k) {                                       \
            float d0 = fmaf(az[k], t0.z, fmaf(ay[k], t0.y, fmaf(ax[k], t0.x, t0.w))); \
            float d1 = fmaf(az[k], t1.z, fmaf(ay[k], t1.y, fmaf(ax[k], t1.x, t1.w))); \
            mn[k] = fminf(fminf(d0, d1), mn[k]);                              \
        }                                                                     \
    }

__global__ __launch_bounds__(TPB, 4)   // 4 waves/EU -> 2 blocks/CU, VGPR<=128
void chamfer_main(const float* __restrict__ pred,
                  const float* __restrict__ tgt,
                  float* __restrict__ blkpart /* [NBLK] */)
{
    int bid = blockIdx.x;
    int dir = bid >> 8;               // 0..1
    int b   = (bid >> 5) & 7;         // batch
    int qt  = bid & 31;               // query tile of 128

    const float* qsrc = dir ? tgt  : pred;
    const float* csrc = dir ? pred : tgt;

    __shared__ float4 sc[PHPTS];      // 32 KB; reused as reduce scratch later
    __shared__ float  acc[TPB / 64];

    int tid = threadIdx.x;
    int qg  = tid & (NQG - 1);        // fast index -> 4 distinct slices/wave
    int sl  = tid >> 4;

    // ---- this thread's 8 consecutive queries: 6 coalesced dwordx4 ----
    const float4* q4 = reinterpret_cast<const float4*>(
        qsrc + ((size_t)b * NPTS + (size_t)qt * QB) * 3);
    float4 v0 = q4[qg * 6 + 0];
    float4 v1 = q4[qg * 6 + 1];
    float4 v2 = q4[qg * 6 + 2];
    float4 v3 = q4[qg * 6 + 3];
    float4 v4 = q4[qg * 6 + 4];
    float4 v5 = q4[qg * 6 + 5];

    float ax[QPT], ay[QPT], az[QPT], mn[QPT];
    {
        float qx[QPT], qy[QPT], qz[QPT];
        qx[0]=v0.x; qy[0]=v0.y; qz[0]=v0.z;
        qx[1]=v0.w; qy[1]=v1.x; qz[1]=v1.y;
        qx[2]=v1.z; qy[2]=v1.w; qz[2]=v2.x;
        qx[3]=v2.y; qy[3]=v2.z; qz[3]=v2.w;
        qx[4]=v3.x; qy[4]=v3.y; qz[4]=v3.z;
        qx[5]=v3.w; qy[5]=v4.x; qz[5]=v4.y;
        qx[6]=v4.z; qy[6]=v4.w; qz[6]=v5.x;
        qx[7]=v5.y; qy[7]=v5.z; qz[7]=v5.w;
#pragma unroll
        for (int i = 0; i < QPT; ++i) {
            ax[i] = -2.0f * qx[i];
            ay[i] = -2.0f * qy[i];
            az[i] = -2.0f * qz[i];
            mn[i] = 3.0e38f;
        }
    }

    const float4* t4 = reinterpret_cast<const float4*>(csrc + (size_t)b * NPTS * 3);

    // ---- phase 0 staging: 4 points = 3 coalesced dwordx4 per thread ----
    float4 r0 = t4[tid * 3 + 0];
    float4 r1 = t4[tid * 3 + 1];
    float4 r2 = t4[tid * 3 + 2];
    sc[tid*4+0] = make_float4(r0.x, r0.y, r0.z, r0.x*r0.x + r0.y*r0.y + r0.z*r0.z);
    sc[tid*4+1] = make_float4(r0.w, r1.x, r1.y, r0.w*r0.w + r1.x*r1.x + r1.y*r1.y);
    sc[tid*4+2] = make_float4(r1.z, r1.w, r2.x, r1.z*r1.z + r1.w*r1.w + r2.x*r2.x);
    sc[tid*4+3] = make_float4(r2.y, r2.z, r2.w, r2.y*r2.y + r2.z*r2.z + r2.w*r2.w);
    __syncthreads();

    // phase 1 staging loads issued now; latency hides under phase-0 compute
    float4 s0 = t4[1536 + tid * 3 + 0];
    float4 s1 = t4[1536 + tid * 3 + 1];
    float4 s2 = t4[1536 + tid * 3 + 2];

    {
        const float4* sbase = sc + sl * SLICE;
        INNER_LOOP(sbase)
    }
    __syncthreads();                   // all reads of phase-0 sc done

    sc[tid*4+0] = make_float4(s0.x, s0.y, s0.z, s0.x*s0.x + s0.y*s0.y + s0.z*s0.z);
    sc[tid*4+1] = make_float4(s0.w, s1.x, s1.y, s0.w*s0.w + s1.x*s1.x + s1.y*s1.y);
    sc[tid*4+2] = make_float4(s1.z, s1.w, s2.x, s1.z*s1.z + s1.w*s1.w + s2.x*s2.x);
    sc[tid*4+3] = make_float4(s2.y, s2.z, s2.w, s2.y*s2.y + s2.z*s2.z + s2.w*s2.w);
    __syncthreads();

    {
        const float4* sbase = sc + sl * SLICE;
        INNER_LOOP(sbase)
    }
    __syncthreads();                   // compute done; sc reusable as scratch

    // ---- in-block cross-slice reduce ----
    float* scratch = (float*)sc;       // [NSL][QB] floats = 16 KB
#pragma unroll
    for (int r = 0; r < QPT; ++r)
        scratch[sl * QB + qg * QPT + r] = mn[r];
    __syncthreads();

    float val = 0.0f;
    if (tid < QB) {                    // one query per thread
        float m = scratch[tid];
#pragma unroll 8
        for (int s = 1; s < NSL; ++s)
            m = fminf(m, scratch[s * QB + tid]);   // lane-contiguous
        const float* qp = qsrc + ((size_t)b * NPTS + (size_t)qt * QB + tid) * 3;
        float x = qp[0], y = qp[1], z = qp[2];     // L1-hot
        val = x*x + y*y + z*z + m;
    }
#pragma unroll
    for (int o = 32; o; o >>= 1) val += __shfl_down(val, o);
    int lane = tid & 63, wid = tid >> 6;
    if (lane == 0) acc[wid] = val;
    __syncthreads();
    if (tid == 0) {
        float s = 0.0f;
#pragma unroll
        for (int i = 0; i < TPB / 64; ++i) s += acc[i];
        blkpart[bid] = s;
    }
}

// node 2: sum 512 block partials, write scalar (plain store, deterministic).
__global__ __launch_bounds__(TPB)
void chamfer_final(const float* __restrict__ blkpart,
                   float* __restrict__ out)
{
    float s = blkpart[threadIdx.x];
#pragma unroll
    for (int o = 32; o; o >>= 1) s += __shfl_down(s, o);
    __shared__ float acc[TPB / 64];
    int lane = threadIdx.x & 63, wid = threadIdx.x >> 6;
    if (lane == 0) acc[wid] = s;
    __syncthreads();
    if (threadIdx.x == 0) {
        float t = 0.0f;
#pragma unroll
        for (int i = 0; i < TPB / 64; ++i) t += acc[i];
        out[0] = t * (1.0f / (BATCH * NPTS));
    }
}

// ---- fallback (no usable ws): block owns 256 queries over full M ----
#define FTPB  256
#define CHUNK 512
#define NCH   (NPTS / CHUNK)

__global__ __launch_bounds__(FTPB)
void chamfer_fallback(const float* __restrict__ pred,
                      const float* __restrict__ tgt,
                      float* __restrict__ out)
{
    int bid = blockIdx.x;
    const int per_dir = BATCH * (NPTS / FTPB);
    int dir = bid / per_dir;
    int r   = bid - dir * per_dir;
    int b   = r / (NPTS / FTPB);
    int qt  = r % (NPTS / FTPB);

    const float* qsrc = dir ? tgt  : pred;
    const float* csrc = dir ? pred : tgt;

    __shared__ float4 sc[CHUNK];
    int q = qt * FTPB + threadIdx.x;
    const float* qp = qsrc + (size_t)(b * NPTS + q) * 3;
    float x = qp[0], y = qp[1], z = qp[2];
    float ax = -2.0f * x, ay = -2.0f * y, az = -2.0f * z;
    float w = x * x + y * y + z * z;
    float mn = 3.0e38f;

    for (int ch = 0; ch < NCH; ++ch) {
        __syncthreads();
        const float* cbase = csrc + (size_t)(b * NPTS + ch * CHUNK) * 3;
        for (int p = threadIdx.x; p < CHUNK; p += FTPB) {
            float tx = cbase[3 * p + 0];
            float ty = cbase[3 * p + 1];
            float tz = cbase[3 * p + 2];
            sc[p] = make_float4(tx, ty, tz, tx * tx + ty * ty + tz * tz);
        }
        __syncthreads();
#pragma unroll 4
        for (int j = 0; j < CHUNK; ++j) {
            float4 t = sc[j];
            float d = fmaf(az, t.z, fmaf(ay, t.y, fmaf(ax, t.x, t.w)));
            mn = fminf(mn, d);
        }
    }
    mn += w;
#pragma unroll
    for (int o = 32; o; o >>= 1) mn += __shfl_down(mn, o);
    __shared__ float acc[FTPB / 64];
    int lane = threadIdx.x & 63, wid = threadIdx.x >> 6;
    if (lane == 0) acc[wid] = mn;
    __syncthreads();
    if (threadIdx.x == 0) {
        float s = 0.0f;
#pragma unroll
        for (int i = 0; i < FTPB / 64; ++i) s += acc[i];
        atomicAdd(out, s * (1.0f / (BATCH * NPTS)));
    }
}

extern "C" void kernel_launch(void* const* d_in, const int* in_sizes, int n_in,
                              void* d_out, int out_size, void* d_ws, size_t ws_size,
                              hipStream_t stream)
{
    const float* pred = (const float*)d_in[0];
    const float* tgt  = (const float*)d_in[1];
    float* out = (float*)d_out;

    if (ws_size >= NBLK * sizeof(float)) {
        float* blkpart = (float*)d_ws;
        chamfer_main<<<NBLK, TPB, 0, stream>>>(pred, tgt, blkpart);
        chamfer_final<<<1, TPB, 0, stream>>>(blkpart, out);
    } else {
        hipMemsetAsync(d_out, 0, sizeof(float), stream);
        chamfer_fallback<<<2 * BATCH * (NPTS / FTPB), FTPB, 0, stream>>>(pred, tgt, out);
    }
}